// Round 8
// baseline (679.474 us; speedup 1.0000x reference)
//
#include <hip/hip_runtime.h>
#include <hip/hip_bf16.h>
#include <math.h>

#define N_NODES 8192
#define IN_FEATS 512
#define N_EDGES 262144
#define NUM_HEADS 8
#define OUT_FEATS 64
#define HD (NUM_HEADS * OUT_FEATS) /* 512 */
#define TOPK 10
#define NEG_INF -9e15f
#define MAXD 128
#define EID_MASK 0x3FFFF  /* 18 bits */
#define NGRP 8            /* dst groups == XCDs */
#define GRP_SHIFT 10      /* 1024 nodes per group */

// ---------------- GEMM: C[8192,512] = feat[8192,512] @ W[512,512]^T ----------------
// 128x128 tile, 1024 thr = 4 sub-blocks of 256; sub q computes K quarter [q*128, q*128+128).
// 8x8 per-thread fragments, XOR-swizzled single-buffered per-sub LDS tiles (64KB total),
// 4 waves/SIMD so LDS-return latency hides under other waves' VALU. Deterministic
// LDS accumulator combine q0+q1+q2+q3. Writes f32 C and bf16 C16.
__device__ __forceinline__ int swz(int row, int k4) {
  return k4 ^ (4 * (((row & 7) ^ ((row >> 3) & 7)) & 7));
}

__global__ __launch_bounds__(1024, 4) void gemm_nt(const float* __restrict__ A,
                                                   const float* __restrict__ B,
                                                   float* __restrict__ C,
                                                   ushort* __restrict__ C16) {
  __shared__ char smem[65536];
  int tid = threadIdx.x;
  int sub = tid >> 8;          // K quarter 0..3
  int stid = tid & 255;
  int tx = stid & 15, ty = stid >> 4;
  int brow = blockIdx.x * 128, bcol = blockIdx.y * 128;
  int kbase = sub * 128;

  float (*Asub)[16] = (float(*)[16])(smem + sub * 8192);            // [128][16]
  float (*Bsub)[16] = (float(*)[16])(smem + 32768 + sub * 8192);    // [128][16]

  int sr = stid >> 1;          // staging row 0..127
  int skc = (stid & 1) * 8;    // staging k-offset 0 or 8
  const float* gA = A + (size_t)(brow + sr) * IN_FEATS + kbase + skc;
  const float* gB = B + (size_t)(bcol + sr) * IN_FEATS + kbase + skc;
  // swizzle within 16-float row: chunk index 0..3
  int w0 = (skc ^ (4 * ((sr ^ (sr >> 3)) & 1))) & 15;      // simple 2-chunk swizzle
  int w1 = w0 ^ 4;

  float acc[8][8];
#pragma unroll
  for (int i = 0; i < 8; i++)
#pragma unroll
    for (int j = 0; j < 8; j++) acc[i][j] = 0.f;

  float4 ra0 = *(const float4*)gA;
  float4 ra1 = *(const float4*)(gA + 4);
  float4 rb0 = *(const float4*)gB;
  float4 rb1 = *(const float4*)(gB + 4);

  const int NT = 8;  // 128 K per sub / 16
  for (int t = 0; t < NT; ++t) {
    __syncthreads();
    *(float4*)&Asub[sr][w0] = ra0; *(float4*)&Asub[sr][w1] = ra1;
    *(float4*)&Bsub[sr][w0] = rb0; *(float4*)&Bsub[sr][w1] = rb1;
    if (t + 1 < NT) {
      const float* pA = gA + (t + 1) * 16;
      const float* pB = gB + (t + 1) * 16;
      ra0 = *(const float4*)pA; ra1 = *(const float4*)(pA + 4);
      rb0 = *(const float4*)pB; rb1 = *(const float4*)(pB + 4);
    }
    __syncthreads();
#pragma unroll
    for (int g = 0; g < 4; ++g) {
      float4 av[8], bv[8];
#pragma unroll
      for (int i = 0; i < 8; i++) {
        int r = ty * 8 + i;
        int c = (g * 4) ^ (4 * ((r ^ (r >> 3)) & 1));
        av[i] = *(const float4*)&Asub[r][c & 15];
      }
#pragma unroll
      for (int j = 0; j < 8; j++) {
        int c2 = tx * 8 + j;
        int c = (g * 4) ^ (4 * ((c2 ^ (c2 >> 3)) & 1));
        bv[j] = *(const float4*)&Bsub[c2][c & 15];
      }
#pragma unroll
      for (int i = 0; i < 8; i++)
#pragma unroll
        for (int j = 0; j < 8; j++) {
          acc[i][j] = fmaf(av[i].x, bv[j].x, acc[i][j]);
          acc[i][j] = fmaf(av[i].y, bv[j].y, acc[i][j]);
          acc[i][j] = fmaf(av[i].z, bv[j].z, acc[i][j]);
          acc[i][j] = fmaf(av[i].w, bv[j].w, acc[i][j]);
        }
    }
  }

  // deterministic combine: acc_total = q0 + q1 + q2 + q3 via padded LDS exchange
  float (*xch)[33] = (float(*)[33])smem;  // [256][33] = 33792B
  __syncthreads();
#pragma unroll
  for (int r = 0; r < 2; ++r) {
#pragma unroll
    for (int q = 1; q < 4; ++q) {
      if (sub == q) {
#pragma unroll
        for (int k = 0; k < 32; ++k) {
          int idx = r * 32 + k;
          xch[stid][k] = acc[idx >> 3][idx & 7];
        }
      }
      __syncthreads();
      if (sub == 0) {
#pragma unroll
        for (int k = 0; k < 32; ++k) {
          int idx = r * 32 + k;
          acc[idx >> 3][idx & 7] += xch[stid][k];
        }
      }
      __syncthreads();
    }
  }

  if (sub == 0) {
#pragma unroll
    for (int i = 0; i < 8; i++) {
      int row = brow + ty * 8 + i;
      float* cp = C + (size_t)row * HD + bcol + tx * 8;
      *(float4*)cp = make_float4(acc[i][0], acc[i][1], acc[i][2], acc[i][3]);
      *(float4*)(cp + 4) = make_float4(acc[i][4], acc[i][5], acc[i][6], acc[i][7]);
      ushort u[8];
#pragma unroll
      for (int j = 0; j < 8; j++) u[j] = __bfloat16_as_ushort(__float2bfloat16(acc[i][j]));
      uint4 q;
      q.x = (unsigned)u[0] | ((unsigned)u[1] << 16);
      q.y = (unsigned)u[2] | ((unsigned)u[3] << 16);
      q.z = (unsigned)u[4] | ((unsigned)u[5] << 16);
      q.w = (unsigned)u[6] | ((unsigned)u[7] << 16);
      *(uint4*)(C16 + (size_t)row * HD + bcol + tx * 8) = q;
    }
  }
}

// ---------------- CSR build ----------------
__global__ __launch_bounds__(256) void histo(const int* __restrict__ src, const int* __restrict__ dst,
                                             int* __restrict__ cnt_s, int* __restrict__ cnt_d) {
  int e = blockIdx.x * blockDim.x + threadIdx.x;
  if (e < N_EDGES) {
    atomicAdd(&cnt_s[src[e]], 1);
    atomicAdd(&cnt_d[dst[e]], 1);
  }
}

__global__ __launch_bounds__(1024) void scan2(const int* __restrict__ cnt_s, const int* __restrict__ cnt_d,
                                              int* __restrict__ rp_s, int* __restrict__ rp_d) {
  __shared__ int ls[1024];
  const int* cnt = blockIdx.x ? cnt_d : cnt_s;
  int* rp = blockIdx.x ? rp_d : rp_s;
  int t = threadIdx.x;
  int base = t * 8;
  int v[8]; int s = 0;
#pragma unroll
  for (int i = 0; i < 8; i++) { v[i] = cnt[base + i]; s += v[i]; }
  ls[t] = s;
  __syncthreads();
  for (int off = 1; off < 1024; off <<= 1) {
    int x = (t >= off) ? ls[t - off] : 0;
    __syncthreads();
    ls[t] += x;
    __syncthreads();
  }
  int excl = (t == 0) ? 0 : ls[t - 1];
#pragma unroll
  for (int i = 0; i < 8; i++) { rp[base + i] = excl; excl += v[i]; }
  if (t == 1023) rp[N_NODES] = excl;
}

__global__ __launch_bounds__(256) void scatter_csr(const int* __restrict__ src, const int* __restrict__ dst,
                                                   const int* __restrict__ rp_s, const int* __restrict__ rp_d,
                                                   int* __restrict__ fill_s, int* __restrict__ fill_d,
                                                   int* __restrict__ cs, int* __restrict__ cd) {
  int e = blockIdx.x * blockDim.x + threadIdx.x;
  if (e < N_EDGES) {
    int p = rp_s[src[e]] + atomicAdd(&fill_s[src[e]], 1);
    cs[p] = e;
    int q = rp_d[dst[e]] + atomicAdd(&fill_d[dst[e]], 1);
    cd[q] = e;
  }
}

// ---------------- barrier-free in-wave bitonic sort + per-row dst-group offsets ----------------
__global__ __launch_bounds__(256) void sort_rows_bitonic(const int* __restrict__ rp_s,
                                                         const int* __restrict__ rp_d,
                                                         const int* __restrict__ dst,
                                                         int* __restrict__ cs, int* __restrict__ cd,
                                                         int* __restrict__ keys_s,
                                                         int* __restrict__ grp_off) {
  int wave = (blockIdx.x * blockDim.x + threadIdx.x) >> 6;
  int lane = threadIdx.x & 63;
  bool is_s = wave < N_NODES;
  int r = is_s ? wave : wave - N_NODES;
  const int* rp = is_s ? rp_s : rp_d;
  int b = rp[r], e2 = rp[r + 1];
  int len = e2 - b; if (len > 128) len = 128;

  int x0 = 0x7FFFFFFF, x1 = 0x7FFFFFFF;
  if (lane < len) {
    int e = is_s ? cs[b + lane] : cd[b + lane];
    x0 = is_s ? ((dst[e] << 18) | e) : e;
  }
  if (lane + 64 < len) {
    int e = is_s ? cs[b + lane + 64] : cd[b + lane + 64];
    x1 = is_s ? ((dst[e] << 18) | e) : e;
  }

  for (int s = 2; s <= 64; s <<= 1) {
    bool asc1 = ((64 & s) == 0);
    for (int d = s >> 1; d >= 1; d >>= 1) {
      {
        int y = __shfl_xor(x0, d);
        bool keepmin = (((lane & d) == 0) == ((lane & s) == 0));
        x0 = keepmin ? min(x0, y) : max(x0, y);
      }
      {
        int y = __shfl_xor(x1, d);
        bool asc = asc1 ? ((lane & s) == 0) : false;
        bool keepmin = (((lane & d) == 0) == asc);
        x1 = keepmin ? min(x1, y) : max(x1, y);
      }
    }
  }
  { int lo = min(x0, x1), hi = max(x0, x1); x0 = lo; x1 = hi; }
  for (int d = 32; d >= 1; d >>= 1) {
    {
      int y = __shfl_xor(x0, d);
      bool keepmin = ((lane & d) == 0);
      x0 = keepmin ? min(x0, y) : max(x0, y);
    }
    {
      int y = __shfl_xor(x1, d);
      bool keepmin = ((lane & d) == 0);
      x1 = keepmin ? min(x1, y) : max(x1, y);
    }
  }

  if (lane < len) {
    if (is_s) { cs[b + lane] = x0 & EID_MASK; keys_s[b + lane] = x0; }
    else cd[b + lane] = x0;
  }
  if (lane + 64 < len) {
    if (is_s) { cs[b + lane + 64] = x1 & EID_MASK; keys_s[b + lane + 64] = x1; }
    else cd[b + lane + 64] = x1;
  }

  // per-row dst-group start offsets (absolute indices into the row)
  if (is_s) {
    if (lane == 0) grp_off[r * NGRP] = b;
    if (lane >= 1 && lane < NGRP) {
      int bound = lane << (GRP_SHIFT + 18);
      int cnt = __popcll(__ballot(x0 < bound)) + __popcll(__ballot(x1 < bound));
      grp_off[r * NGRP + lane] = b + cnt;
    } else {
      __ballot(x0 < 0); __ballot(x1 < 0);  // keep ballot wave-collective
    }
  }
}

// ---------------- SDDMM, dst-group tiled with XCD affinity ----------------
// block = (32 src rows) x (dst group g = blockIdx&7 -> XCD g). Group g's fsrc slice
// (2MB) stays L2-resident on XCD g; random gathers become L2 hits. Each wave walks
// 8 rows' group-g slices (src fragment register-resident per row).
__global__ __launch_bounds__(256) void edge_scores_tiled(const float* __restrict__ fsrc,
                                                         const int* __restrict__ dst,
                                                         const float* __restrict__ trans,
                                                         const int* __restrict__ rp_s,
                                                         const int* __restrict__ cs,
                                                         const int* __restrict__ grp_off,
                                                         float* __restrict__ escore, float* __restrict__ val) {
  int g = blockIdx.x & 7;
  int sb = blockIdx.x >> 3;
  int w = threadIdx.x >> 6;
  int lane = threadIdx.x & 63;
  int head = lane >> 3;
  bool leader = (lane & 7) == 0;
  int rbase = sb * 32 + w * 8;
#pragma unroll 1
  for (int rr = 0; rr < 8; ++rr) {
    int r = rbase + rr;
    int b = grp_off[r * NGRP + g];
    int e2 = (g == 7) ? rp_s[r + 1] : grp_off[r * NGRP + g + 1];
    int cap = rp_s[r] + 128;
    if (e2 > cap) e2 = cap;
    if (b >= e2) continue;
    const float4* ps = (const float4*)(fsrc + (size_t)r * HD) + lane * 2;
    float4 s0 = ps[0], s1 = ps[1];
    for (int i = b; i < e2; i++) {
      int e = cs[i];
      const float4* pd = (const float4*)(fsrc + (size_t)dst[e] * HD) + lane * 2;
      float4 d0 = pd[0], d1 = pd[1];
      float dot = s0.x * d0.x + s0.y * d0.y + s0.z * d0.z + s0.w * d0.w
                + s1.x * d1.x + s1.y * d1.y + s1.z * d1.z + s1.w * d1.w;
      dot += __shfl_xor(dot, 1);
      dot += __shfl_xor(dot, 2);
      dot += __shfl_xor(dot, 4);
      if (leader) escore[(size_t)e * 8 + head] = dot;
      float x = leader ? dot * trans[e] : 0.f;
      x += __shfl_xor(x, 8);
      x += __shfl_xor(x, 16);
      x += __shfl_xor(x, 32);
      if (lane == 0) val[e] = x;
    }
  }
}

// ---------------- wave-per-row top-10 threshold + run-combined values ----------------
__global__ __launch_bounds__(256) void topk_wave(const int* __restrict__ rp_s,
                                                 const int* __restrict__ keys_s,
                                                 const float* __restrict__ val,
                                                 float* __restrict__ aval,
                                                 float* __restrict__ thresh) {
  int wave = (blockIdx.x * blockDim.x + threadIdx.x) >> 6;
  int lane = threadIdx.x & 63;
  if (wave >= N_NODES) return;
  int b = rp_s[wave], e2 = rp_s[wave + 1];
  int len = e2 - b; if (len > 128) len = 128;
  float c[2];
#pragma unroll
  for (int k = 0; k < 2; k++) {
    int i = lane + 64 * k;
    float cv = 0.f;
    if (i < len) {
      int key = keys_s[b + i];
      int d = key >> 18;
      int prevd = (i == 0) ? -1 : (keys_s[b + i - 1] >> 18);
      if (d != prevd) {
        float s = val[key & EID_MASK];
        for (int j = i + 1; j < len; j++) {
          int kj = keys_s[b + j];
          if ((kj >> 18) != d) break;
          s += val[kj & EID_MASK];
        }
        cv = s;
        aval[b + i] = s;
      } else {
        aval[b + i] = 0.f;
      }
    }
    c[k] = cv;
  }
  float t10 = 0.f;
  for (int t = 0; t < 10; t++) {
    float m = fmaxf(c[0], c[1]);
#pragma unroll
    for (int off = 1; off < 64; off <<= 1) m = fmaxf(m, __shfl_xor(m, off));
    if (m <= 0.f) { t10 = 0.f; break; }
    t10 = m;
    if (t == 9) break;
    unsigned long long b0 = __ballot(c[0] == m);
    if (b0) {
      int l = __ffsll(b0) - 1;
      if (lane == l) c[0] = -1e30f;
    } else {
      unsigned long long b1 = __ballot(c[1] == m);
      int l = __ffsll(b1) - 1;
      if (lane == l) c[1] = -1e30f;
    }
  }
  if (lane == 0) thresh[wave] = fmaxf(t10, 0.f);
}

// ---------------- per-edge reverse-pair mask via binary search ----------------
__global__ __launch_bounds__(256) void cond_edges(const int* __restrict__ src, const int* __restrict__ dst,
                                                  const int* __restrict__ rp_s,
                                                  const int* __restrict__ keys_s,
                                                  const float* __restrict__ aval,
                                                  const float* __restrict__ thresh,
                                                  unsigned char* __restrict__ cond) {
  int e = blockIdx.x * blockDim.x + threadIdx.x;
  if (e >= N_EDGES) return;
  int s = src[e], d = dst[e];
  int lo = rp_s[d], hi = rp_s[d + 1];
  int end = hi;
  int target = s << 18;
  while (lo < hi) {
    int mid = (lo + hi) >> 1;
    if (keys_s[mid] < target) lo = mid + 1; else hi = mid;
  }
  float a = 0.f;
  if (lo < end && (keys_s[lo] >> 18) == s) a = aval[lo];
  cond[e] = (a < thresh[d]) ? 1 : 0;
}

// ---------------- per-dst-node: mask + edge softmax + aggregation (bf16 gather, 2x unroll) ----------------
__global__ __launch_bounds__(64) void dst_softmax_agg(const int* __restrict__ rp_d, const int* __restrict__ cd,
                                                      const int* __restrict__ src,
                                                      const unsigned char* __restrict__ cond,
                                                      const float* __restrict__ escore,
                                                      const ushort* __restrict__ fsrc16,
                                                      float* __restrict__ out) {
  __shared__ float p_lds[MAXD * 9];
  __shared__ int u_lds[MAXD];
  int v = blockIdx.x;
  int lane = threadIdx.x;
  int rb = rp_d[v], re = rp_d[v + 1];
  int d = re - rb;
  if (d > MAXD) d = MAXD;

  float sc[2][8];
  float m[8];
#pragma unroll
  for (int h = 0; h < 8; h++) m[h] = -3.0e38f;

#pragma unroll
  for (int k = 0; k < 2; k++) {
    int il = lane + 64 * k;
    if (il < d) {
      int ei = cd[rb + il];
      int u = src[ei];
      u_lds[il] = u;
      bool cmask = cond[ei] != 0;
      const float* sp = escore + (size_t)ei * 8;
      float4 s0 = *(const float4*)sp;
      float4 s1 = *(const float4*)(sp + 4);
      float ss[8] = {s0.x, s0.y, s0.z, s0.w, s1.x, s1.y, s1.z, s1.w};
#pragma unroll
      for (int h = 0; h < 8; h++) {
        float x = cmask ? NEG_INF : ss[h];
        sc[k][h] = x;
        m[h] = fmaxf(m[h], x);
      }
    } else {
#pragma unroll
      for (int h = 0; h < 8; h++) sc[k][h] = -3.0e38f;
    }
  }
#pragma unroll
  for (int off = 1; off < 64; off <<= 1)
#pragma unroll
    for (int h = 0; h < 8; h++) m[h] = fmaxf(m[h], __shfl_xor(m[h], off));

  float z[8];
#pragma unroll
  for (int h = 0; h < 8; h++) z[h] = 0.f;
#pragma unroll
  for (int k = 0; k < 2; k++) {
    int il = lane + 64 * k;
    if (il < d) {
#pragma unroll
      for (int h = 0; h < 8; h++) {
        float p = expf(sc[k][h] - m[h]);
        z[h] += p;
        p_lds[il * 9 + h] = p;
      }
    }
  }
#pragma unroll
  for (int off = 1; off < 64; off <<= 1)
#pragma unroll
    for (int h = 0; h < 8; h++) z[h] += __shfl_xor(z[h], off);

  int myh = lane >> 3;
  float zh = 0.f;
#pragma unroll
  for (int h = 0; h < 8; h++) zh = (h == myh) ? z[h] : zh;
  float invZ = (d > 0) ? (1.0f / zh) : 0.f;

  __syncthreads();

  float accA[8], accB[8];
#pragma unroll
  for (int j = 0; j < 8; j++) { accA[j] = 0.f; accB[j] = 0.f; }
  int i = 0;
  for (; i + 2 <= d; i += 2) {
    float wA = p_lds[i * 9 + myh] * invZ;
    float wB = p_lds[(i + 1) * 9 + myh] * invZ;
    const ushort* fpA = fsrc16 + (size_t)u_lds[i] * HD + lane * 8;
    const ushort* fpB = fsrc16 + (size_t)u_lds[i + 1] * HD + lane * 8;
    uint4 qA = *(const uint4*)fpA;
    uint4 qB = *(const uint4*)fpB;
    accA[0] = fmaf(wA, __uint_as_float(qA.x << 16), accA[0]);
    accA[1] = fmaf(wA, __uint_as_float(qA.x & 0xFFFF0000u), accA[1]);
    accA[2] = fmaf(wA, __uint_as_float(qA.y << 16), accA[2]);
    accA[3] = fmaf(wA, __uint_as_float(qA.y & 0xFFFF0000u), accA[3]);
    accA[4] = fmaf(wA, __uint_as_float(qA.z << 16), accA[4]);
    accA[5] = fmaf(wA, __uint_as_float(qA.z & 0xFFFF0000u), accA[5]);
    accA[6] = fmaf(wA, __uint_as_float(qA.w << 16), accA[6]);
    accA[7] = fmaf(wA, __uint_as_float(qA.w & 0xFFFF0000u), accA[7]);
    accB[0] = fmaf(wB, __uint_as_float(qB.x << 16), accB[0]);
    accB[1] = fmaf(wB, __uint_as_float(qB.x & 0xFFFF0000u), accB[1]);
    accB[2] = fmaf(wB, __uint_as_float(qB.y << 16), accB[2]);
    accB[3] = fmaf(wB, __uint_as_float(qB.y & 0xFFFF0000u), accB[3]);
    accB[4] = fmaf(wB, __uint_as_float(qB.z << 16), accB[4]);
    accB[5] = fmaf(wB, __uint_as_float(qB.z & 0xFFFF0000u), accB[5]);
    accB[6] = fmaf(wB, __uint_as_float(qB.w << 16), accB[6]);
    accB[7] = fmaf(wB, __uint_as_float(qB.w & 0xFFFF0000u), accB[7]);
  }
  if (i < d) {
    float w = p_lds[i * 9 + myh] * invZ;
    const ushort* fp = fsrc16 + (size_t)u_lds[i] * HD + lane * 8;
    uint4 q = *(const uint4*)fp;
    accA[0] = fmaf(w, __uint_as_float(q.x << 16), accA[0]);
    accA[1] = fmaf(w, __uint_as_float(q.x & 0xFFFF0000u), accA[1]);
    accA[2] = fmaf(w, __uint_as_float(q.y << 16), accA[2]);
    accA[3] = fmaf(w, __uint_as_float(q.y & 0xFFFF0000u), accA[3]);
    accA[4] = fmaf(w, __uint_as_float(q.z << 16), accA[4]);
    accA[5] = fmaf(w, __uint_as_float(q.z & 0xFFFF0000u), accA[5]);
    accA[6] = fmaf(w, __uint_as_float(q.w << 16), accA[6]);
    accA[7] = fmaf(w, __uint_as_float(q.w & 0xFFFF0000u), accA[7]);
  }
  float* op = out + (size_t)v * HD + lane * 8;
  *(float4*)op = make_float4(accA[0] + accB[0], accA[1] + accB[1], accA[2] + accB[2], accA[3] + accB[3]);
  *(float4*)(op + 4) = make_float4(accA[4] + accB[4], accA[5] + accB[5], accA[6] + accB[6], accA[7] + accB[7]);
}

extern "C" void kernel_launch(void* const* d_in, const int* in_sizes, int n_in,
                              void* d_out, int out_size, void* d_ws, size_t ws_size,
                              hipStream_t stream) {
  const float* feat = (const float*)d_in[0];
  const float* fcw = (const float*)d_in[1];
  const float* trans = (const float*)d_in[2];
  const int* src = (const int*)d_in[3];
  const int* dst = (const int*)d_in[4];
  float* out = (float*)d_out;

  char* ws = (char*)d_ws;
  size_t off = 0;
  auto alloc = [&](size_t bytes) -> void* {
    size_t o = off;
    off = (off + bytes + 255) & ~(size_t)255;
    return (void*)(ws + o);
  };
  float* fsrc = (float*)alloc((size_t)N_NODES * HD * 4);
  ushort* fsrc16 = (ushort*)alloc((size_t)N_NODES * HD * 2);
  float* escore = (float*)alloc((size_t)N_EDGES * 8 * 4);
  float* val = (float*)alloc((size_t)N_EDGES * 4);
  int* cnt = (int*)alloc((size_t)4 * N_NODES * 4);
  int* rp_s = (int*)alloc((size_t)(N_NODES + 1) * 4);
  int* rp_d = (int*)alloc((size_t)(N_NODES + 1) * 4);
  int* cs = (int*)alloc((size_t)N_EDGES * 4);
  int* cd = (int*)alloc((size_t)N_EDGES * 4);
  int* keys_s = (int*)alloc((size_t)N_EDGES * 4);
  float* aval = (float*)alloc((size_t)N_EDGES * 4);
  float* thresh = (float*)alloc((size_t)N_NODES * 4);
  int* grp_off = (int*)alloc((size_t)N_NODES * NGRP * 4);
  unsigned char* cond = (unsigned char*)alloc((size_t)N_EDGES);
  if (off > ws_size) return;

  int* cnt_s = cnt;
  int* cnt_d = cnt + N_NODES;
  int* fill_s = cnt + 2 * N_NODES;
  int* fill_d = cnt + 3 * N_NODES;

  hipMemsetAsync(cnt, 0, (size_t)4 * N_NODES * 4, stream);
  histo<<<N_EDGES / 256, 256, 0, stream>>>(src, dst, cnt_s, cnt_d);
  scan2<<<2, 1024, 0, stream>>>(cnt_s, cnt_d, rp_s, rp_d);
  scatter_csr<<<N_EDGES / 256, 256, 0, stream>>>(src, dst, rp_s, rp_d, fill_s, fill_d, cs, cd);
  sort_rows_bitonic<<<(2 * N_NODES * 64) / 256, 256, 0, stream>>>(rp_s, rp_d, dst, cs, cd, keys_s, grp_off);
  gemm_nt<<<dim3(N_NODES / 128, HD / 128), 1024, 0, stream>>>(feat, fcw, fsrc, fsrc16);
  edge_scores_tiled<<<NGRP * (N_NODES / 32), 256, 0, stream>>>(fsrc, dst, trans, rp_s, cs, grp_off, escore, val);
  topk_wave<<<(N_NODES * 64) / 256, 256, 0, stream>>>(rp_s, keys_s, val, aval, thresh);
  cond_edges<<<N_EDGES / 256, 256, 0, stream>>>(src, dst, rp_s, keys_s, aval, thresh, cond);
  dst_softmax_agg<<<N_NODES, 64, 0, stream>>>(rp_d, cd, src, cond, escore, fsrc16, out);
}

// Round 9
// 256.127 us; speedup vs baseline: 2.6529x; 2.6529x over previous
//
#include <hip/hip_runtime.h>
#include <hip/hip_bf16.h>
#include <math.h>

#define N_NODES 8192
#define IN_FEATS 512
#define N_EDGES 262144
#define NUM_HEADS 8
#define OUT_FEATS 64
#define HD (NUM_HEADS * OUT_FEATS) /* 512 */
#define TOPK 10
#define NEG_INF -9e15f
#define MAXD 128
#define EID_MASK 0x3FFFF  /* 18 bits */

// ---------------- GEMM: C[8192,512] = feat[8192,512] @ W[512,512]^T ----------------
// R7 version (measured 80 us): 128x128 tile, 512 thr = 2 sub-blocks of 256 (K half each),
// 8x8 frags, XOR-swizzled single-buffered per-sub LDS tiles (64KB), deterministic combine.
__device__ __forceinline__ int swz(int row, int k4) {
  return k4 ^ (4 * (((row & 7) ^ ((row >> 3) & 7)) & 7));
}

__global__ __launch_bounds__(512, 2) void gemm_nt(const float* __restrict__ A,
                                                  const float* __restrict__ B,
                                                  float* __restrict__ C,
                                                  ushort* __restrict__ C16) {
  __shared__ char smem[65536];
  int tid = threadIdx.x;
  int sub = tid >> 8;          // K half
  int stid = tid & 255;
  int tx = stid & 15, ty = stid >> 4;
  int brow = blockIdx.x * 128, bcol = blockIdx.y * 128;
  int kbase = sub * 256;

  float (*Asub)[32] = (float(*)[32])(smem + sub * 16384);           // [128][32]
  float (*Bsub)[32] = (float(*)[32])(smem + 32768 + sub * 16384);   // [128][32]

  int sr = stid >> 1;          // staging row 0..127
  int skc = (stid & 1) * 8;    // staging k-offset 0 or 8
  const float* gA = A + (size_t)(brow + sr) * IN_FEATS + kbase + skc;
  const float* gB = B + (size_t)(bcol + sr) * IN_FEATS + kbase + skc;
  int w0 = swz(sr, skc), w1 = swz(sr, skc + 4);

  float acc[8][8];
#pragma unroll
  for (int i = 0; i < 8; i++)
#pragma unroll
    for (int j = 0; j < 8; j++) acc[i][j] = 0.f;

  float4 ra0 = *(const float4*)gA;
  float4 ra1 = *(const float4*)(gA + 4);
  float4 rb0 = *(const float4*)gB;
  float4 rb1 = *(const float4*)(gB + 4);

  const int NT = 16;  // 256 K per sub / 16
  for (int t = 0; t < NT; ++t) {
    __syncthreads();  // previous compute done before overwrite
    *(float4*)&Asub[sr][w0] = ra0; *(float4*)&Asub[sr][w1] = ra1;
    *(float4*)&Bsub[sr][w0] = rb0; *(float4*)&Bsub[sr][w1] = rb1;
    if (t + 1 < NT) {
      const float* pA = gA + (t + 1) * 16;
      const float* pB = gB + (t + 1) * 16;
      ra0 = *(const float4*)pA; ra1 = *(const float4*)(pA + 4);
      rb0 = *(const float4*)pB; rb1 = *(const float4*)(pB + 4);
    }
    __syncthreads();
#pragma unroll
    for (int g = 0; g < 4; ++g) {
      float4 av[8], bv[8];
#pragma unroll
      for (int i = 0; i < 8; i++) {
        int r = ty * 8 + i;
        av[i] = *(const float4*)&Asub[r][swz(r, g * 4)];
      }
#pragma unroll
      for (int j = 0; j < 8; j++) {
        int c = tx * 8 + j;
        bv[j] = *(const float4*)&Bsub[c][swz(c, g * 4)];
      }
#pragma unroll
      for (int i = 0; i < 8; i++)
#pragma unroll
        for (int j = 0; j < 8; j++) {
          acc[i][j] = fmaf(av[i].x, bv[j].x, acc[i][j]);
          acc[i][j] = fmaf(av[i].y, bv[j].y, acc[i][j]);
          acc[i][j] = fmaf(av[i].z, bv[j].z, acc[i][j]);
          acc[i][j] = fmaf(av[i].w, bv[j].w, acc[i][j]);
        }
    }
  }

  // deterministic combine: acc_total = acc_sub0 + acc_sub1 (exchange via padded LDS)
  float (*xch)[33] = (float(*)[33])smem;  // [256][33] = 33792B, 2-way bank alias (free)
  __syncthreads();
#pragma unroll
  for (int r = 0; r < 2; ++r) {
    if (sub == 1) {
#pragma unroll
      for (int k = 0; k < 32; ++k) {
        int idx = r * 32 + k;
        xch[stid][k] = acc[idx >> 3][idx & 7];
      }
    }
    __syncthreads();
    if (sub == 0) {
#pragma unroll
      for (int k = 0; k < 32; ++k) {
        int idx = r * 32 + k;
        acc[idx >> 3][idx & 7] += xch[stid][k];
      }
    }
    __syncthreads();
  }

  if (sub == 0) {
#pragma unroll
    for (int i = 0; i < 8; i++) {
      int row = brow + ty * 8 + i;
      float* cp = C + (size_t)row * HD + bcol + tx * 8;
      *(float4*)cp = make_float4(acc[i][0], acc[i][1], acc[i][2], acc[i][3]);
      *(float4*)(cp + 4) = make_float4(acc[i][4], acc[i][5], acc[i][6], acc[i][7]);
      ushort u[8];
#pragma unroll
      for (int j = 0; j < 8; j++) u[j] = __bfloat16_as_ushort(__float2bfloat16(acc[i][j]));
      uint4 q;
      q.x = (unsigned)u[0] | ((unsigned)u[1] << 16);
      q.y = (unsigned)u[2] | ((unsigned)u[3] << 16);
      q.z = (unsigned)u[4] | ((unsigned)u[5] << 16);
      q.w = (unsigned)u[6] | ((unsigned)u[7] << 16);
      *(uint4*)(C16 + (size_t)row * HD + bcol + tx * 8) = q;
    }
  }
}

// ---------------- CSR build ----------------
__global__ __launch_bounds__(256) void histo(const int* __restrict__ src, const int* __restrict__ dst,
                                             int* __restrict__ cnt_s, int* __restrict__ cnt_d) {
  int e = blockIdx.x * blockDim.x + threadIdx.x;
  if (e < N_EDGES) {
    atomicAdd(&cnt_s[src[e]], 1);
    atomicAdd(&cnt_d[dst[e]], 1);
  }
}

__global__ __launch_bounds__(1024) void scan2(const int* __restrict__ cnt_s, const int* __restrict__ cnt_d,
                                              int* __restrict__ rp_s, int* __restrict__ rp_d) {
  __shared__ int ls[1024];
  const int* cnt = blockIdx.x ? cnt_d : cnt_s;
  int* rp = blockIdx.x ? rp_d : rp_s;
  int t = threadIdx.x;
  int base = t * 8;
  int v[8]; int s = 0;
#pragma unroll
  for (int i = 0; i < 8; i++) { v[i] = cnt[base + i]; s += v[i]; }
  ls[t] = s;
  __syncthreads();
  for (int off = 1; off < 1024; off <<= 1) {
    int x = (t >= off) ? ls[t - off] : 0;
    __syncthreads();
    ls[t] += x;
    __syncthreads();
  }
  int excl = (t == 0) ? 0 : ls[t - 1];
#pragma unroll
  for (int i = 0; i < 8; i++) { rp[base + i] = excl; excl += v[i]; }
  if (t == 1023) rp[N_NODES] = excl;
}

__global__ __launch_bounds__(256) void scatter_csr(const int* __restrict__ src, const int* __restrict__ dst,
                                                   const int* __restrict__ rp_s, const int* __restrict__ rp_d,
                                                   int* __restrict__ fill_s, int* __restrict__ fill_d,
                                                   int* __restrict__ cs, int* __restrict__ cd) {
  int e = blockIdx.x * blockDim.x + threadIdx.x;
  if (e < N_EDGES) {
    int p = rp_s[src[e]] + atomicAdd(&fill_s[src[e]], 1);
    cs[p] = e;
    int q = rp_d[dst[e]] + atomicAdd(&fill_d[dst[e]], 1);
    cd[q] = e;
  }
}

// ---------------- barrier-free in-wave bitonic sort (128 elems, 2/lane) ----------------
__global__ __launch_bounds__(256) void sort_rows_bitonic(const int* __restrict__ rp_s,
                                                         const int* __restrict__ rp_d,
                                                         const int* __restrict__ dst,
                                                         int* __restrict__ cs, int* __restrict__ cd,
                                                         int* __restrict__ keys_s) {
  int wave = (blockIdx.x * blockDim.x + threadIdx.x) >> 6;
  int lane = threadIdx.x & 63;
  bool is_s = wave < N_NODES;
  int r = is_s ? wave : wave - N_NODES;
  const int* rp = is_s ? rp_s : rp_d;
  int b = rp[r], e2 = rp[r + 1];
  int len = e2 - b; if (len > 128) len = 128;

  int x0 = 0x7FFFFFFF, x1 = 0x7FFFFFFF;
  if (lane < len) {
    int e = is_s ? cs[b + lane] : cd[b + lane];
    x0 = is_s ? ((dst[e] << 18) | e) : e;
  }
  if (lane + 64 < len) {
    int e = is_s ? cs[b + lane + 64] : cd[b + lane + 64];
    x1 = is_s ? ((dst[e] << 18) | e) : e;
  }

  for (int s = 2; s <= 64; s <<= 1) {
    bool asc1 = ((64 & s) == 0);
    for (int d = s >> 1; d >= 1; d >>= 1) {
      {
        int y = __shfl_xor(x0, d);
        bool keepmin = (((lane & d) == 0) == ((lane & s) == 0));
        x0 = keepmin ? min(x0, y) : max(x0, y);
      }
      {
        int y = __shfl_xor(x1, d);
        bool asc = asc1 ? ((lane & s) == 0) : false;
        bool keepmin = (((lane & d) == 0) == asc);
        x1 = keepmin ? min(x1, y) : max(x1, y);
      }
    }
  }
  { int lo = min(x0, x1), hi = max(x0, x1); x0 = lo; x1 = hi; }
  for (int d = 32; d >= 1; d >>= 1) {
    {
      int y = __shfl_xor(x0, d);
      bool keepmin = ((lane & d) == 0);
      x0 = keepmin ? min(x0, y) : max(x0, y);
    }
    {
      int y = __shfl_xor(x1, d);
      bool keepmin = ((lane & d) == 0);
      x1 = keepmin ? min(x1, y) : max(x1, y);
    }
  }

  if (lane < len) {
    if (is_s) { cs[b + lane] = x0 & EID_MASK; keys_s[b + lane] = x0; }
    else cd[b + lane] = x0;
  }
  if (lane + 64 < len) {
    if (is_s) { cs[b + lane + 64] = x1 & EID_MASK; keys_s[b + lane + 64] = x1; }
    else cd[b + lane + 64] = x1;
  }
}

// ---------------- per-edge per-head scores (SDDMM), wave per SRC ROW, 4x unroll ----------------
__global__ __launch_bounds__(256) void edge_scores_row(const float* __restrict__ fsrc,
                                                       const int* __restrict__ dst,
                                                       const float* __restrict__ trans,
                                                       const int* __restrict__ rp_s,
                                                       const int* __restrict__ cs,
                                                       float* __restrict__ escore, float* __restrict__ val) {
  int wave = (blockIdx.x * blockDim.x + threadIdx.x) >> 6;
  int lane = threadIdx.x & 63;
  if (wave >= N_NODES) return;
  int b = rp_s[wave], e2 = rp_s[wave + 1];
  if (b == e2) return;
  const float4* ps = (const float4*)(fsrc + (size_t)wave * HD) + lane * 2;
  float4 s0 = ps[0], s1 = ps[1];
  int head = lane >> 3;
  bool leader = (lane & 7) == 0;
  for (int i = b; i < e2; i += 4) {
    int n = e2 - i; if (n > 4) n = 4;
    int ee[4];
    float4 d0[4], d1[4];
#pragma unroll
    for (int k = 0; k < 4; k++) {
      int idx = (k < n) ? (i + k) : i;   // clamped duplicate (write-guarded below)
      int e = cs[idx];
      ee[k] = e;
      const float4* pd = (const float4*)(fsrc + (size_t)dst[e] * HD) + lane * 2;
      d0[k] = pd[0];
      d1[k] = pd[1];
    }
#pragma unroll
    for (int k = 0; k < 4; k++) {
      if (k < n) {
        float dot = s0.x * d0[k].x + s0.y * d0[k].y + s0.z * d0[k].z + s0.w * d0[k].w
                  + s1.x * d1[k].x + s1.y * d1[k].y + s1.z * d1[k].z + s1.w * d1[k].w;
        dot += __shfl_xor(dot, 1);
        dot += __shfl_xor(dot, 2);
        dot += __shfl_xor(dot, 4);
        int e = ee[k];
        if (leader) escore[(size_t)e * 8 + head] = dot;
        float x = leader ? dot * trans[e] : 0.f;
        x += __shfl_xor(x, 8);
        x += __shfl_xor(x, 16);
        x += __shfl_xor(x, 32);
        if (lane == 0) val[e] = x;
      }
    }
  }
}

// ---------------- wave-per-row top-10 threshold + run-combined values ----------------
__global__ __launch_bounds__(256) void topk_wave(const int* __restrict__ rp_s,
                                                 const int* __restrict__ keys_s,
                                                 const float* __restrict__ val,
                                                 float* __restrict__ aval,
                                                 float* __restrict__ thresh) {
  int wave = (blockIdx.x * blockDim.x + threadIdx.x) >> 6;
  int lane = threadIdx.x & 63;
  if (wave >= N_NODES) return;
  int b = rp_s[wave], e2 = rp_s[wave + 1];
  int len = e2 - b; if (len > 128) len = 128;
  float c[2];
#pragma unroll
  for (int k = 0; k < 2; k++) {
    int i = lane + 64 * k;
    float cv = 0.f;
    if (i < len) {
      int key = keys_s[b + i];
      int d = key >> 18;
      int prevd = (i == 0) ? -1 : (keys_s[b + i - 1] >> 18);
      if (d != prevd) {
        float s = val[key & EID_MASK];
        for (int j = i + 1; j < len; j++) {
          int kj = keys_s[b + j];
          if ((kj >> 18) != d) break;
          s += val[kj & EID_MASK];
        }
        cv = s;
        aval[b + i] = s;
      } else {
        aval[b + i] = 0.f;
      }
    }
    c[k] = cv;
  }
  float t10 = 0.f;
  for (int t = 0; t < 10; t++) {
    float m = fmaxf(c[0], c[1]);
#pragma unroll
    for (int off = 1; off < 64; off <<= 1) m = fmaxf(m, __shfl_xor(m, off));
    if (m <= 0.f) { t10 = 0.f; break; }
    t10 = m;
    if (t == 9) break;
    unsigned long long b0 = __ballot(c[0] == m);
    if (b0) {
      int l = __ffsll(b0) - 1;
      if (lane == l) c[0] = -1e30f;
    } else {
      unsigned long long b1 = __ballot(c[1] == m);
      int l = __ffsll(b1) - 1;
      if (lane == l) c[1] = -1e30f;
    }
  }
  if (lane == 0) thresh[wave] = fmaxf(t10, 0.f);
}

// ---------------- per-edge reverse-pair mask via binary search ----------------
__global__ __launch_bounds__(256) void cond_edges(const int* __restrict__ src, const int* __restrict__ dst,
                                                  const int* __restrict__ rp_s,
                                                  const int* __restrict__ keys_s,
                                                  const float* __restrict__ aval,
                                                  const float* __restrict__ thresh,
                                                  unsigned char* __restrict__ cond) {
  int e = blockIdx.x * blockDim.x + threadIdx.x;
  if (e >= N_EDGES) return;
  int s = src[e], d = dst[e];
  int lo = rp_s[d], hi = rp_s[d + 1];
  int end = hi;
  int target = s << 18;
  while (lo < hi) {
    int mid = (lo + hi) >> 1;
    if (keys_s[mid] < target) lo = mid + 1; else hi = mid;
  }
  float a = 0.f;
  if (lo < end && (keys_s[lo] >> 18) == s) a = aval[lo];
  cond[e] = (a < thresh[d]) ? 1 : 0;
}

// ---------------- per-dst-node: mask + edge softmax + aggregation ----------------
// 4 nodes per 256-thread block (4 waves) for occupancy; 4x-unrolled bf16 gather (MLP).
__global__ __launch_bounds__(256) void dst_softmax_agg(const int* __restrict__ rp_d, const int* __restrict__ cd,
                                                       const int* __restrict__ src,
                                                       const unsigned char* __restrict__ cond,
                                                       const float* __restrict__ escore,
                                                       const ushort* __restrict__ fsrc16,
                                                       float* __restrict__ out) {
  __shared__ float p_lds[4][MAXD * 9];
  __shared__ int u_lds[4][MAXD];
  int w = threadIdx.x >> 6;
  int lane = threadIdx.x & 63;
  int v = blockIdx.x * 4 + w;
  float* pl = p_lds[w];
  int* ul = u_lds[w];
  int rb = rp_d[v], re = rp_d[v + 1];
  int d = re - rb;
  if (d > MAXD) d = MAXD;

  float sc[2][8];
  float m[8];
#pragma unroll
  for (int h = 0; h < 8; h++) m[h] = -3.0e38f;

#pragma unroll
  for (int k = 0; k < 2; k++) {
    int il = lane + 64 * k;
    if (il < d) {
      int ei = cd[rb + il];
      int u = src[ei];
      ul[il] = u;
      bool cmask = cond[ei] != 0;
      const float* sp = escore + (size_t)ei * 8;
      float4 s0 = *(const float4*)sp;
      float4 s1 = *(const float4*)(sp + 4);
      float ss[8] = {s0.x, s0.y, s0.z, s0.w, s1.x, s1.y, s1.z, s1.w};
#pragma unroll
      for (int h = 0; h < 8; h++) {
        float x = cmask ? NEG_INF : ss[h];
        sc[k][h] = x;
        m[h] = fmaxf(m[h], x);
      }
    } else {
#pragma unroll
      for (int h = 0; h < 8; h++) sc[k][h] = -3.0e38f;
    }
  }
#pragma unroll
  for (int off = 1; off < 64; off <<= 1)
#pragma unroll
    for (int h = 0; h < 8; h++) m[h] = fmaxf(m[h], __shfl_xor(m[h], off));

  float z[8];
#pragma unroll
  for (int h = 0; h < 8; h++) z[h] = 0.f;
#pragma unroll
  for (int k = 0; k < 2; k++) {
    int il = lane + 64 * k;
    if (il < d) {
#pragma unroll
      for (int h = 0; h < 8; h++) {
        float p = expf(sc[k][h] - m[h]);
        z[h] += p;
        pl[il * 9 + h] = p;
      }
    }
  }
#pragma unroll
  for (int off = 1; off < 64; off <<= 1)
#pragma unroll
    for (int h = 0; h < 8; h++) z[h] += __shfl_xor(z[h], off);

  int myh = lane >> 3;
  float zh = 0.f;
#pragma unroll
  for (int h = 0; h < 8; h++) zh = (h == myh) ? z[h] : zh;
  float invZ = (d > 0) ? (1.0f / zh) : 0.f;

  __syncthreads();

  float a0[8], a1[8], a2[8], a3[8];
#pragma unroll
  for (int j = 0; j < 8; j++) { a0[j] = 0.f; a1[j] = 0.f; a2[j] = 0.f; a3[j] = 0.f; }
  int i = 0;
  for (; i + 4 <= d; i += 4) {
    float w0 = pl[(i + 0) * 9 + myh] * invZ;
    float w1 = pl[(i + 1) * 9 + myh] * invZ;
    float w2 = pl[(i + 2) * 9 + myh] * invZ;
    float w3 = pl[(i + 3) * 9 + myh] * invZ;
    uint4 q0 = *(const uint4*)(fsrc16 + (size_t)ul[i + 0] * HD + lane * 8);
    uint4 q1 = *(const uint4*)(fsrc16 + (size_t)ul[i + 1] * HD + lane * 8);
    uint4 q2 = *(const uint4*)(fsrc16 + (size_t)ul[i + 2] * HD + lane * 8);
    uint4 q3 = *(const uint4*)(fsrc16 + (size_t)ul[i + 3] * HD + lane * 8);
    a0[0] = fmaf(w0, __uint_as_float(q0.x << 16), a0[0]);
    a0[1] = fmaf(w0, __uint_as_float(q0.x & 0xFFFF0000u), a0[1]);
    a0[2] = fmaf(w0, __uint_as_float(q0.y << 16), a0[2]);
    a0[3] = fmaf(w0, __uint_as_float(q0.y & 0xFFFF0000u), a0[3]);
    a0[4] = fmaf(w0, __uint_as_float(q0.z << 16), a0[4]);
    a0[5] = fmaf(w0, __uint_as_float(q0.z & 0xFFFF0000u), a0[5]);
    a0[6] = fmaf(w0, __uint_as_float(q0.w << 16), a0[6]);
    a0[7] = fmaf(w0, __uint_as_float(q0.w & 0xFFFF0000u), a0[7]);
    a1[0] = fmaf(w1, __uint_as_float(q1.x << 16), a1[0]);
    a1[1] = fmaf(w1, __uint_as_float(q1.x & 0xFFFF0000u), a1[1]);
    a1[2] = fmaf(w1, __uint_as_float(q1.y << 16), a1[2]);
    a1[3] = fmaf(w1, __uint_as_float(q1.y & 0xFFFF0000u), a1[3]);
    a1[4] = fmaf(w1, __uint_as_float(q1.z << 16), a1[4]);
    a1[5] = fmaf(w1, __uint_as_float(q1.z & 0xFFFF0000u), a1[5]);
    a1[6] = fmaf(w1, __uint_as_float(q1.w << 16), a1[6]);
    a1[7] = fmaf(w1, __uint_as_float(q1.w & 0xFFFF0000u), a1[7]);
    a2[0] = fmaf(w2, __uint_as_float(q2.x << 16), a2[0]);
    a2[1] = fmaf(w2, __uint_as_float(q2.x & 0xFFFF0000u), a2[1]);
    a2[2] = fmaf(w2, __uint_as_float(q2.y << 16), a2[2]);
    a2[3] = fmaf(w2, __uint_as_float(q2.y & 0xFFFF0000u), a2[3]);
    a2[4] = fmaf(w2, __uint_as_float(q2.z << 16), a2[4]);
    a2[5] = fmaf(w2, __uint_as_float(q2.z & 0xFFFF0000u), a2[5]);
    a2[6] = fmaf(w2, __uint_as_float(q2.w << 16), a2[6]);
    a2[7] = fmaf(w2, __uint_as_float(q2.w & 0xFFFF0000u), a2[7]);
    a3[0] = fmaf(w3, __uint_as_float(q3.x << 16), a3[0]);
    a3[1] = fmaf(w3, __uint_as_float(q3.x & 0xFFFF0000u), a3[1]);
    a3[2] = fmaf(w3, __uint_as_float(q3.y << 16), a3[2]);
    a3[3] = fmaf(w3, __uint_as_float(q3.y & 0xFFFF0000u), a3[3]);
    a3[4] = fmaf(w3, __uint_as_float(q3.z << 16), a3[4]);
    a3[5] = fmaf(w3, __uint_as_float(q3.z & 0xFFFF0000u), a3[5]);
    a3[6] = fmaf(w3, __uint_as_float(q3.w << 16), a3[6]);
    a3[7] = fmaf(w3, __uint_as_float(q3.w & 0xFFFF0000u), a3[7]);
  }
  for (; i < d; ++i) {
    float ww = pl[i * 9 + myh] * invZ;
    uint4 q = *(const uint4*)(fsrc16 + (size_t)ul[i] * HD + lane * 8);
    a0[0] = fmaf(ww, __uint_as_float(q.x << 16), a0[0]);
    a0[1] = fmaf(ww, __uint_as_float(q.x & 0xFFFF0000u), a0[1]);
    a0[2] = fmaf(ww, __uint_as_float(q.y << 16), a0[2]);
    a0[3] = fmaf(ww, __uint_as_float(q.y & 0xFFFF0000u), a0[3]);
    a0[4] = fmaf(ww, __uint_as_float(q.z << 16), a0[4]);
    a0[5] = fmaf(ww, __uint_as_float(q.z & 0xFFFF0000u), a0[5]);
    a0[6] = fmaf(ww, __uint_as_float(q.w << 16), a0[6]);
    a0[7] = fmaf(ww, __uint_as_float(q.w & 0xFFFF0000u), a0[7]);
  }
  float* op = out + (size_t)v * HD + lane * 8;
  *(float4*)op = make_float4((a0[0] + a1[0]) + (a2[0] + a3[0]),
                             (a0[1] + a1[1]) + (a2[1] + a3[1]),
                             (a0[2] + a1[2]) + (a2[2] + a3[2]),
                             (a0[3] + a1[3]) + (a2[3] + a3[3]));
  *(float4*)(op + 4) = make_float4((a0[4] + a1[4]) + (a2[4] + a3[4]),
                                   (a0[5] + a1[5]) + (a2[5] + a3[5]),
                                   (a0[6] + a1[6]) + (a2[6] + a3[6]),
                                   (a0[7] + a1[7]) + (a2[7] + a3[7]));
}

extern "C" void kernel_launch(void* const* d_in, const int* in_sizes, int n_in,
                              void* d_out, int out_size, void* d_ws, size_t ws_size,
                              hipStream_t stream) {
  const float* feat = (const float*)d_in[0];
  const float* fcw = (const float*)d_in[1];
  const float* trans = (const float*)d_in[2];
  const int* src = (const int*)d_in[3];
  const int* dst = (const int*)d_in[4];
  float* out = (float*)d_out;

  char* ws = (char*)d_ws;
  size_t off = 0;
  auto alloc = [&](size_t bytes) -> void* {
    size_t o = off;
    off = (off + bytes + 255) & ~(size_t)255;
    return (void*)(ws + o);
  };
  float* fsrc = (float*)alloc((size_t)N_NODES * HD * 4);
  ushort* fsrc16 = (ushort*)alloc((size_t)N_NODES * HD * 2);
  float* escore = (float*)alloc((size_t)N_EDGES * 8 * 4);
  float* val = (float*)alloc((size_t)N_EDGES * 4);
  int* cnt = (int*)alloc((size_t)4 * N_NODES * 4);
  int* rp_s = (int*)alloc((size_t)(N_NODES + 1) * 4);
  int* rp_d = (int*)alloc((size_t)(N_NODES + 1) * 4);
  int* cs = (int*)alloc((size_t)N_EDGES * 4);
  int* cd = (int*)alloc((size_t)N_EDGES * 4);
  int* keys_s = (int*)alloc((size_t)N_EDGES * 4);
  float* aval = (float*)alloc((size_t)N_EDGES * 4);
  float* thresh = (float*)alloc((size_t)N_NODES * 4);
  unsigned char* cond = (unsigned char*)alloc((size_t)N_EDGES);
  if (off > ws_size) return;

  int* cnt_s = cnt;
  int* cnt_d = cnt + N_NODES;
  int* fill_s = cnt + 2 * N_NODES;
  int* fill_d = cnt + 3 * N_NODES;

  hipMemsetAsync(cnt, 0, (size_t)4 * N_NODES * 4, stream);
  histo<<<N_EDGES / 256, 256, 0, stream>>>(src, dst, cnt_s, cnt_d);
  scan2<<<2, 1024, 0, stream>>>(cnt_s, cnt_d, rp_s, rp_d);
  scatter_csr<<<N_EDGES / 256, 256, 0, stream>>>(src, dst, rp_s, rp_d, fill_s, fill_d, cs, cd);
  sort_rows_bitonic<<<(2 * N_NODES * 64) / 256, 256, 0, stream>>>(rp_s, rp_d, dst, cs, cd, keys_s);
  gemm_nt<<<dim3(N_NODES / 128, HD / 128), 512, 0, stream>>>(feat, fcw, fsrc, fsrc16);
  edge_scores_row<<<(N_NODES * 64) / 256, 256, 0, stream>>>(fsrc, dst, trans, rp_s, cs, escore, val);
  topk_wave<<<(N_NODES * 64) / 256, 256, 0, stream>>>(rp_s, keys_s, val, aval, thresh);
  cond_edges<<<N_EDGES / 256, 256, 0, stream>>>(src, dst, rp_s, keys_s, aval, thresh, cond);
  dst_softmax_agg<<<N_NODES / 4, 256, 0, stream>>>(rp_d, cd, src, cond, escore, fsrc16, out);
}

// Round 10
// 252.839 us; speedup vs baseline: 2.6874x; 1.0130x over previous
//
#include <hip/hip_runtime.h>
#include <hip/hip_bf16.h>
#include <math.h>

#define N_NODES 8192
#define IN_FEATS 512
#define N_EDGES 262144
#define NUM_HEADS 8
#define OUT_FEATS 64
#define HD (NUM_HEADS * OUT_FEATS) /* 512 */
#define TOPK 10
#define NEG_INF -9e15f
#define MAXD 128
#define EID_MASK 0x3FFFF  /* 18 bits */
#define NGRP 8            /* dst groups == XCDs */

// ---------------- GEMM: C[8192,512] = feat[8192,512] @ W[512,512]^T ----------------
// Measured 80 us: 128x128 tile, 512 thr = 2 sub-blocks of 256 (K half each),
// 8x8 frags, XOR-swizzled single-buffered per-sub LDS tiles (64KB), deterministic combine.
__device__ __forceinline__ int swz(int row, int k4) {
  return k4 ^ (4 * (((row & 7) ^ ((row >> 3) & 7)) & 7));
}

__global__ __launch_bounds__(512, 2) void gemm_nt(const float* __restrict__ A,
                                                  const float* __restrict__ B,
                                                  float* __restrict__ C,
                                                  ushort* __restrict__ C16) {
  __shared__ char smem[65536];
  int tid = threadIdx.x;
  int sub = tid >> 8;          // K half
  int stid = tid & 255;
  int tx = stid & 15, ty = stid >> 4;
  int brow = blockIdx.x * 128, bcol = blockIdx.y * 128;
  int kbase = sub * 256;

  float (*Asub)[32] = (float(*)[32])(smem + sub * 16384);           // [128][32]
  float (*Bsub)[32] = (float(*)[32])(smem + 32768 + sub * 16384);   // [128][32]

  int sr = stid >> 1;          // staging row 0..127
  int skc = (stid & 1) * 8;    // staging k-offset 0 or 8
  const float* gA = A + (size_t)(brow + sr) * IN_FEATS + kbase + skc;
  const float* gB = B + (size_t)(bcol + sr) * IN_FEATS + kbase + skc;
  int w0 = swz(sr, skc), w1 = swz(sr, skc + 4);

  float acc[8][8];
#pragma unroll
  for (int i = 0; i < 8; i++)
#pragma unroll
    for (int j = 0; j < 8; j++) acc[i][j] = 0.f;

  float4 ra0 = *(const float4*)gA;
  float4 ra1 = *(const float4*)(gA + 4);
  float4 rb0 = *(const float4*)gB;
  float4 rb1 = *(const float4*)(gB + 4);

  const int NT = 16;  // 256 K per sub / 16
  for (int t = 0; t < NT; ++t) {
    __syncthreads();  // previous compute done before overwrite
    *(float4*)&Asub[sr][w0] = ra0; *(float4*)&Asub[sr][w1] = ra1;
    *(float4*)&Bsub[sr][w0] = rb0; *(float4*)&Bsub[sr][w1] = rb1;
    if (t + 1 < NT) {
      const float* pA = gA + (t + 1) * 16;
      const float* pB = gB + (t + 1) * 16;
      ra0 = *(const float4*)pA; ra1 = *(const float4*)(pA + 4);
      rb0 = *(const float4*)pB; rb1 = *(const float4*)(pB + 4);
    }
    __syncthreads();
#pragma unroll
    for (int g = 0; g < 4; ++g) {
      float4 av[8], bv[8];
#pragma unroll
      for (int i = 0; i < 8; i++) {
        int r = ty * 8 + i;
        av[i] = *(const float4*)&Asub[r][swz(r, g * 4)];
      }
#pragma unroll
      for (int j = 0; j < 8; j++) {
        int c = tx * 8 + j;
        bv[j] = *(const float4*)&Bsub[c][swz(c, g * 4)];
      }
#pragma unroll
      for (int i = 0; i < 8; i++)
#pragma unroll
        for (int j = 0; j < 8; j++) {
          acc[i][j] = fmaf(av[i].x, bv[j].x, acc[i][j]);
          acc[i][j] = fmaf(av[i].y, bv[j].y, acc[i][j]);
          acc[i][j] = fmaf(av[i].z, bv[j].z, acc[i][j]);
          acc[i][j] = fmaf(av[i].w, bv[j].w, acc[i][j]);
        }
    }
  }

  // deterministic combine: acc_total = acc_sub0 + acc_sub1 (exchange via padded LDS)
  float (*xch)[33] = (float(*)[33])smem;  // [256][33] = 33792B, 2-way bank alias (free)
  __syncthreads();
#pragma unroll
  for (int r = 0; r < 2; ++r) {
    if (sub == 1) {
#pragma unroll
      for (int k = 0; k < 32; ++k) {
        int idx = r * 32 + k;
        xch[stid][k] = acc[idx >> 3][idx & 7];
      }
    }
    __syncthreads();
    if (sub == 0) {
#pragma unroll
      for (int k = 0; k < 32; ++k) {
        int idx = r * 32 + k;
        acc[idx >> 3][idx & 7] += xch[stid][k];
      }
    }
    __syncthreads();
  }

  if (sub == 0) {
#pragma unroll
    for (int i = 0; i < 8; i++) {
      int row = brow + ty * 8 + i;
      float* cp = C + (size_t)row * HD + bcol + tx * 8;
      *(float4*)cp = make_float4(acc[i][0], acc[i][1], acc[i][2], acc[i][3]);
      *(float4*)(cp + 4) = make_float4(acc[i][4], acc[i][5], acc[i][6], acc[i][7]);
      ushort u[8];
#pragma unroll
      for (int j = 0; j < 8; j++) u[j] = __bfloat16_as_ushort(__float2bfloat16(acc[i][j]));
      uint4 q;
      q.x = (unsigned)u[0] | ((unsigned)u[1] << 16);
      q.y = (unsigned)u[2] | ((unsigned)u[3] << 16);
      q.z = (unsigned)u[4] | ((unsigned)u[5] << 16);
      q.w = (unsigned)u[6] | ((unsigned)u[7] << 16);
      *(uint4*)(C16 + (size_t)row * HD + bcol + tx * 8) = q;
    }
  }
}

// ---------------- CSR build ----------------
__global__ __launch_bounds__(256) void histo(const int* __restrict__ src, const int* __restrict__ dst,
                                             int* __restrict__ cnt_s, int* __restrict__ cnt_d) {
  int e = blockIdx.x * blockDim.x + threadIdx.x;
  if (e < N_EDGES) {
    atomicAdd(&cnt_s[src[e]], 1);
    atomicAdd(&cnt_d[dst[e]], 1);
  }
}

__global__ __launch_bounds__(1024) void scan2(const int* __restrict__ cnt_s, const int* __restrict__ cnt_d,
                                              int* __restrict__ rp_s, int* __restrict__ rp_d) {
  __shared__ int ls[1024];
  const int* cnt = blockIdx.x ? cnt_d : cnt_s;
  int* rp = blockIdx.x ? rp_d : rp_s;
  int t = threadIdx.x;
  int base = t * 8;
  int v[8]; int s = 0;
#pragma unroll
  for (int i = 0; i < 8; i++) { v[i] = cnt[base + i]; s += v[i]; }
  ls[t] = s;
  __syncthreads();
  for (int off = 1; off < 1024; off <<= 1) {
    int x = (t >= off) ? ls[t - off] : 0;
    __syncthreads();
    ls[t] += x;
    __syncthreads();
  }
  int excl = (t == 0) ? 0 : ls[t - 1];
#pragma unroll
  for (int i = 0; i < 8; i++) { rp[base + i] = excl; excl += v[i]; }
  if (t == 1023) rp[N_NODES] = excl;
}

__global__ __launch_bounds__(256) void scatter_csr(const int* __restrict__ src, const int* __restrict__ dst,
                                                   const int* __restrict__ rp_s, const int* __restrict__ rp_d,
                                                   int* __restrict__ fill_s, int* __restrict__ fill_d,
                                                   int* __restrict__ cs, int* __restrict__ cd) {
  int e = blockIdx.x * blockDim.x + threadIdx.x;
  if (e < N_EDGES) {
    int p = rp_s[src[e]] + atomicAdd(&fill_s[src[e]], 1);
    cs[p] = e;
    int q = rp_d[dst[e]] + atomicAdd(&fill_d[dst[e]], 1);
    cd[q] = e;
  }
}

// ---------------- barrier-free in-wave bitonic sort + CORRECT per-row group offsets ----------------
// group(key) = key>>28 = dst>>10. Starts found via shfl-based run-boundary detection
// (R8's divergent-ballot version produced constant offsets — groups never partitioned).
__global__ __launch_bounds__(256) void sort_rows_bitonic(const int* __restrict__ rp_s,
                                                         const int* __restrict__ rp_d,
                                                         const int* __restrict__ dst,
                                                         int* __restrict__ cs, int* __restrict__ cd,
                                                         int* __restrict__ keys_s,
                                                         int* __restrict__ grp_off) {
  int wave = (blockIdx.x * blockDim.x + threadIdx.x) >> 6;
  int lane = threadIdx.x & 63;
  bool is_s = wave < N_NODES;
  int r = is_s ? wave : wave - N_NODES;
  const int* rp = is_s ? rp_s : rp_d;
  int b = rp[r], e2 = rp[r + 1];
  int len = e2 - b; if (len > 128) len = 128;

  int x0 = 0x7FFFFFFF, x1 = 0x7FFFFFFF;
  if (lane < len) {
    int e = is_s ? cs[b + lane] : cd[b + lane];
    x0 = is_s ? ((dst[e] << 18) | e) : e;
  }
  if (lane + 64 < len) {
    int e = is_s ? cs[b + lane + 64] : cd[b + lane + 64];
    x1 = is_s ? ((dst[e] << 18) | e) : e;
  }

  for (int s = 2; s <= 64; s <<= 1) {
    bool asc1 = ((64 & s) == 0);
    for (int d = s >> 1; d >= 1; d >>= 1) {
      {
        int y = __shfl_xor(x0, d);
        bool keepmin = (((lane & d) == 0) == ((lane & s) == 0));
        x0 = keepmin ? min(x0, y) : max(x0, y);
      }
      {
        int y = __shfl_xor(x1, d);
        bool asc = asc1 ? ((lane & s) == 0) : false;
        bool keepmin = (((lane & d) == 0) == asc);
        x1 = keepmin ? min(x1, y) : max(x1, y);
      }
    }
  }
  { int lo = min(x0, x1), hi = max(x0, x1); x0 = lo; x1 = hi; }
  for (int d = 32; d >= 1; d >>= 1) {
    {
      int y = __shfl_xor(x0, d);
      bool keepmin = ((lane & d) == 0);
      x0 = keepmin ? min(x0, y) : max(x0, y);
    }
    {
      int y = __shfl_xor(x1, d);
      bool keepmin = ((lane & d) == 0);
      x1 = keepmin ? min(x1, y) : max(x1, y);
    }
  }

  if (lane < len) {
    if (is_s) { cs[b + lane] = x0 & EID_MASK; keys_s[b + lane] = x0; }
    else cd[b + lane] = x0;
  }
  if (lane + 64 < len) {
    if (is_s) { cs[b + lane + 64] = x1 & EID_MASK; keys_s[b + lane + 64] = x1; }
    else cd[b + lane + 64] = x1;
  }

  if (is_s) {
    // per-position group id (8 = padding sentinel)
    int g0 = (lane < len) ? (x0 >> 28) : 8;
    int g1 = (lane + 64 < len) ? (x1 >> 28) : 8;
    int g0p = __shfl_up(g0, 1);
    if (lane == 0) g0p = -1;                 // position 0 has no predecessor
    int g1p = __shfl_up(g1, 1);
    int g0last = __shfl(g0, 63);
    if (lane == 0) g1p = g0last;             // position 64's predecessor is position 63
    for (int gg = g0p + 1; gg <= g0 && gg <= 7; ++gg) grp_off[r * NGRP + gg] = b + lane;
    for (int gg = g1p + 1; gg <= g1 && gg <= 7; ++gg) grp_off[r * NGRP + gg] = b + lane + 64;
    if (lane == 63) {                        // tail groups when len == 128
      for (int gg = g1 + 1; gg <= 7; ++gg) grp_off[r * NGRP + gg] = b + 128;
    }
  }
}

// ---------------- SDDMM, XCD-grouped: one wave = one (src row, dst group) slice ----------------
// g = blockIdx&7 -> XCD g (round-robin dispatch). Group g's fsrc rows (2MB) stay resident
// in XCD g's 4MB L2, so the random dst gathers become L2 hits. 65536 wave-tasks with
// batched 4-wide gathers give the MLP/TLP that R8's serial version lacked.
__global__ __launch_bounds__(256, 4) void edge_scores_grp(const float* __restrict__ fsrc,
                                                          const int* __restrict__ dst,
                                                          const float* __restrict__ trans,
                                                          const int* __restrict__ rp_s,
                                                          const int* __restrict__ cs,
                                                          const int* __restrict__ grp_off,
                                                          float* __restrict__ escore,
                                                          float* __restrict__ val) {
  int g = blockIdx.x & 7;
  int r = (blockIdx.x >> 3) * 4 + (threadIdx.x >> 6);
  int lane = threadIdx.x & 63;
  int b = grp_off[r * NGRP + g];
  int e2 = (g == 7) ? rp_s[r + 1] : grp_off[r * NGRP + g + 1];  // g==7 uncapped: tail edges too
  if (b >= e2) return;
  const float4* ps = (const float4*)(fsrc + (size_t)r * HD) + lane * 2;
  float4 s0 = ps[0], s1 = ps[1];
  int head = lane >> 3;
  bool leader = (lane & 7) == 0;
  for (int i = b; i < e2; i += 4) {
    int n = e2 - i; if (n > 4) n = 4;
    int ee[4];
    float4 d0[4], d1[4];
#pragma unroll
    for (int k = 0; k < 4; k++) {
      int idx = (k < n) ? (i + k) : i;   // clamped duplicate (write-guarded below)
      int e = cs[idx];
      ee[k] = e;
      const float4* pd = (const float4*)(fsrc + (size_t)dst[e] * HD) + lane * 2;
      d0[k] = pd[0];
      d1[k] = pd[1];
    }
#pragma unroll
    for (int k = 0; k < 4; k++) {
      if (k < n) {
        float dot = s0.x * d0[k].x + s0.y * d0[k].y + s0.z * d0[k].z + s0.w * d0[k].w
                  + s1.x * d1[k].x + s1.y * d1[k].y + s1.z * d1[k].z + s1.w * d1[k].w;
        dot += __shfl_xor(dot, 1);
        dot += __shfl_xor(dot, 2);
        dot += __shfl_xor(dot, 4);
        int e = ee[k];
        if (leader) escore[(size_t)e * 8 + head] = dot;
        float x = leader ? dot * trans[e] : 0.f;
        x += __shfl_xor(x, 8);
        x += __shfl_xor(x, 16);
        x += __shfl_xor(x, 32);
        if (lane == 0) val[e] = x;
      }
    }
  }
}

// ---------------- wave-per-row top-10 threshold + run-combined values ----------------
__global__ __launch_bounds__(256) void topk_wave(const int* __restrict__ rp_s,
                                                 const int* __restrict__ keys_s,
                                                 const float* __restrict__ val,
                                                 float* __restrict__ aval,
                                                 float* __restrict__ thresh) {
  int wave = (blockIdx.x * blockDim.x + threadIdx.x) >> 6;
  int lane = threadIdx.x & 63;
  if (wave >= N_NODES) return;
  int b = rp_s[wave], e2 = rp_s[wave + 1];
  int len = e2 - b; if (len > 128) len = 128;
  float c[2];
#pragma unroll
  for (int k = 0; k < 2; k++) {
    int i = lane + 64 * k;
    float cv = 0.f;
    if (i < len) {
      int key = keys_s[b + i];
      int d = key >> 18;
      int prevd = (i == 0) ? -1 : (keys_s[b + i - 1] >> 18);
      if (d != prevd) {
        float s = val[key & EID_MASK];
        for (int j = i + 1; j < len; j++) {
          int kj = keys_s[b + j];
          if ((kj >> 18) != d) break;
          s += val[kj & EID_MASK];
        }
        cv = s;
        aval[b + i] = s;
      } else {
        aval[b + i] = 0.f;
      }
    }
    c[k] = cv;
  }
  float t10 = 0.f;
  for (int t = 0; t < 10; t++) {
    float m = fmaxf(c[0], c[1]);
#pragma unroll
    for (int off = 1; off < 64; off <<= 1) m = fmaxf(m, __shfl_xor(m, off));
    if (m <= 0.f) { t10 = 0.f; break; }
    t10 = m;
    if (t == 9) break;
    unsigned long long b0 = __ballot(c[0] == m);
    if (b0) {
      int l = __ffsll(b0) - 1;
      if (lane == l) c[0] = -1e30f;
    } else {
      unsigned long long b1 = __ballot(c[1] == m);
      int l = __ffsll(b1) - 1;
      if (lane == l) c[1] = -1e30f;
    }
  }
  if (lane == 0) thresh[wave] = fmaxf(t10, 0.f);
}

// ---------------- per-edge reverse-pair mask via binary search ----------------
__global__ __launch_bounds__(256) void cond_edges(const int* __restrict__ src, const int* __restrict__ dst,
                                                  const int* __restrict__ rp_s,
                                                  const int* __restrict__ keys_s,
                                                  const float* __restrict__ aval,
                                                  const float* __restrict__ thresh,
                                                  unsigned char* __restrict__ cond) {
  int e = blockIdx.x * blockDim.x + threadIdx.x;
  if (e >= N_EDGES) return;
  int s = src[e], d = dst[e];
  int lo = rp_s[d], hi = rp_s[d + 1];
  int end = hi;
  int target = s << 18;
  while (lo < hi) {
    int mid = (lo + hi) >> 1;
    if (keys_s[mid] < target) lo = mid + 1; else hi = mid;
  }
  float a = 0.f;
  if (lo < end && (keys_s[lo] >> 18) == s) a = aval[lo];
  cond[e] = (a < thresh[d]) ? 1 : 0;
}

// ---------------- per-dst-node: mask + edge softmax + aggregation ----------------
// 4 nodes per 256-thread block (4 waves); 4x-unrolled bf16 gather (MLP).
__global__ __launch_bounds__(256) void dst_softmax_agg(const int* __restrict__ rp_d, const int* __restrict__ cd,
                                                       const int* __restrict__ src,
                                                       const unsigned char* __restrict__ cond,
                                                       const float* __restrict__ escore,
                                                       const ushort* __restrict__ fsrc16,
                                                       float* __restrict__ out) {
  __shared__ float p_lds[4][MAXD * 9];
  __shared__ int u_lds[4][MAXD];
  int w = threadIdx.x >> 6;
  int lane = threadIdx.x & 63;
  int v = blockIdx.x * 4 + w;
  float* pl = p_lds[w];
  int* ul = u_lds[w];
  int rb = rp_d[v], re = rp_d[v + 1];
  int d = re - rb;
  if (d > MAXD) d = MAXD;

  float sc[2][8];
  float m[8];
#pragma unroll
  for (int h = 0; h < 8; h++) m[h] = -3.0e38f;

#pragma unroll
  for (int k = 0; k < 2; k++) {
    int il = lane + 64 * k;
    if (il < d) {
      int ei = cd[rb + il];
      int u = src[ei];
      ul[il] = u;
      bool cmask = cond[ei] != 0;
      const float* sp = escore + (size_t)ei * 8;
      float4 s0 = *(const float4*)sp;
      float4 s1 = *(const float4*)(sp + 4);
      float ss[8] = {s0.x, s0.y, s0.z, s0.w, s1.x, s1.y, s1.z, s1.w};
#pragma unroll
      for (int h = 0; h < 8; h++) {
        float x = cmask ? NEG_INF : ss[h];
        sc[k][h] = x;
        m[h] = fmaxf(m[h], x);
      }
    } else {
#pragma unroll
      for (int h = 0; h < 8; h++) sc[k][h] = -3.0e38f;
    }
  }
#pragma unroll
  for (int off = 1; off < 64; off <<= 1)
#pragma unroll
    for (int h = 0; h < 8; h++) m[h] = fmaxf(m[h], __shfl_xor(m[h], off));

  float z[8];
#pragma unroll
  for (int h = 0; h < 8; h++) z[h] = 0.f;
#pragma unroll
  for (int k = 0; k < 2; k++) {
    int il = lane + 64 * k;
    if (il < d) {
#pragma unroll
      for (int h = 0; h < 8; h++) {
        float p = expf(sc[k][h] - m[h]);
        z[h] += p;
        pl[il * 9 + h] = p;
      }
    }
  }
#pragma unroll
  for (int off = 1; off < 64; off <<= 1)
#pragma unroll
    for (int h = 0; h < 8; h++) z[h] += __shfl_xor(z[h], off);

  int myh = lane >> 3;
  float zh = 0.f;
#pragma unroll
  for (int h = 0; h < 8; h++) zh = (h == myh) ? z[h] : zh;
  float invZ = (d > 0) ? (1.0f / zh) : 0.f;

  __syncthreads();

  float a0[8], a1[8], a2[8], a3[8];
#pragma unroll
  for (int j = 0; j < 8; j++) { a0[j] = 0.f; a1[j] = 0.f; a2[j] = 0.f; a3[j] = 0.f; }
  int i = 0;
  for (; i + 4 <= d; i += 4) {
    float w0 = pl[(i + 0) * 9 + myh] * invZ;
    float w1 = pl[(i + 1) * 9 + myh] * invZ;
    float w2 = pl[(i + 2) * 9 + myh] * invZ;
    float w3 = pl[(i + 3) * 9 + myh] * invZ;
    uint4 q0 = *(const uint4*)(fsrc16 + (size_t)ul[i + 0] * HD + lane * 8);
    uint4 q1 = *(const uint4*)(fsrc16 + (size_t)ul[i + 1] * HD + lane * 8);
    uint4 q2 = *(const uint4*)(fsrc16 + (size_t)ul[i + 2] * HD + lane * 8);
    uint4 q3 = *(const uint4*)(fsrc16 + (size_t)ul[i + 3] * HD + lane * 8);
    a0[0] = fmaf(w0, __uint_as_float(q0.x << 16), a0[0]);
    a0[1] = fmaf(w0, __uint_as_float(q0.x & 0xFFFF0000u), a0[1]);
    a0[2] = fmaf(w0, __uint_as_float(q0.y << 16), a0[2]);
    a0[3] = fmaf(w0, __uint_as_float(q0.y & 0xFFFF0000u), a0[3]);
    a0[4] = fmaf(w0, __uint_as_float(q0.z << 16), a0[4]);
    a0[5] = fmaf(w0, __uint_as_float(q0.z & 0xFFFF0000u), a0[5]);
    a0[6] = fmaf(w0, __uint_as_float(q0.w << 16), a0[6]);
    a0[7] = fmaf(w0, __uint_as_float(q0.w & 0xFFFF0000u), a0[7]);
    a1[0] = fmaf(w1, __uint_as_float(q1.x << 16), a1[0]);
    a1[1] = fmaf(w1, __uint_as_float(q1.x & 0xFFFF0000u), a1[1]);
    a1[2] = fmaf(w1, __uint_as_float(q1.y << 16), a1[2]);
    a1[3] = fmaf(w1, __uint_as_float(q1.y & 0xFFFF0000u), a1[3]);
    a1[4] = fmaf(w1, __uint_as_float(q1.z << 16), a1[4]);
    a1[5] = fmaf(w1, __uint_as_float(q1.z & 0xFFFF0000u), a1[5]);
    a1[6] = fmaf(w1, __uint_as_float(q1.w << 16), a1[6]);
    a1[7] = fmaf(w1, __uint_as_float(q1.w & 0xFFFF0000u), a1[7]);
    a2[0] = fmaf(w2, __uint_as_float(q2.x << 16), a2[0]);
    a2[1] = fmaf(w2, __uint_as_float(q2.x & 0xFFFF0000u), a2[1]);
    a2[2] = fmaf(w2, __uint_as_float(q2.y << 16), a2[2]);
    a2[3] = fmaf(w2, __uint_as_float(q2.y & 0xFFFF0000u), a2[3]);
    a2[4] = fmaf(w2, __uint_as_float(q2.z << 16), a2[4]);
    a2[5] = fmaf(w2, __uint_as_float(q2.z & 0xFFFF0000u), a2[5]);
    a2[6] = fmaf(w2, __uint_as_float(q2.w << 16), a2[6]);
    a2[7] = fmaf(w2, __uint_as_float(q2.w & 0xFFFF0000u), a2[7]);
    a3[0] = fmaf(w3, __uint_as_float(q3.x << 16), a3[0]);
    a3[1] = fmaf(w3, __uint_as_float(q3.x & 0xFFFF0000u), a3[1]);
    a3[2] = fmaf(w3, __uint_as_float(q3.y << 16), a3[2]);
    a3[3] = fmaf(w3, __uint_as_float(q3.y & 0xFFFF0000u), a3[3]);
    a3[4] = fmaf(w3, __uint_as_float(q3.z << 16), a3[4]);
    a3[5] = fmaf(w3, __uint_as_float(q3.z & 0xFFFF0000u), a3[5]);
    a3[6] = fmaf(w3, __uint_as_float(q3.w << 16), a3[6]);
    a3[7] = fmaf(w3, __uint_as_float(q3.w & 0xFFFF0000u), a3[7]);
  }
  for (; i < d; ++i) {
    float ww = pl[i * 9 + myh] * invZ;
    uint4 q = *(const uint4*)(fsrc16 + (size_t)ul[i] * HD + lane * 8);
    a0[0] = fmaf(ww, __uint_as_float(q.x << 16), a0[0]);
    a0[1] = fmaf(ww, __uint_as_float(q.x & 0xFFFF0000u), a0[1]);
    a0[2] = fmaf(ww, __uint_as_float(q.y << 16), a0[2]);
    a0[3] = fmaf(ww, __uint_as_float(q.y & 0xFFFF0000u), a0[3]);
    a0[4] = fmaf(ww, __uint_as_float(q.z << 16), a0[4]);
    a0[5] = fmaf(ww, __uint_as_float(q.z & 0xFFFF0000u), a0[5]);
    a0[6] = fmaf(ww, __uint_as_float(q.w << 16), a0[6]);
    a0[7] = fmaf(ww, __uint_as_float(q.w & 0xFFFF0000u), a0[7]);
  }
  float* op = out + (size_t)v * HD + lane * 8;
  *(float4*)op = make_float4((a0[0] + a1[0]) + (a2[0] + a3[0]),
                             (a0[1] + a1[1]) + (a2[1] + a3[1]),
                             (a0[2] + a1[2]) + (a2[2] + a3[2]),
                             (a0[3] + a1[3]) + (a2[3] + a3[3]));
  *(float4*)(op + 4) = make_float4((a0[4] + a1[4]) + (a2[4] + a3[4]),
                                   (a0[5] + a1[5]) + (a2[5] + a3[5]),
                                   (a0[6] + a1[6]) + (a2[6] + a3[6]),
                                   (a0[7] + a1[7]) + (a2[7] + a3[7]));
}

extern "C" void kernel_launch(void* const* d_in, const int* in_sizes, int n_in,
                              void* d_out, int out_size, void* d_ws, size_t ws_size,
                              hipStream_t stream) {
  const float* feat = (const float*)d_in[0];
  const float* fcw = (const float*)d_in[1];
  const float* trans = (const float*)d_in[2];
  const int* src = (const int*)d_in[3];
  const int* dst = (const int*)d_in[4];
  float* out = (float*)d_out;

  char* ws = (char*)d_ws;
  size_t off = 0;
  auto alloc = [&](size_t bytes) -> void* {
    size_t o = off;
    off = (off + bytes + 255) & ~(size_t)255;
    return (void*)(ws + o);
  };
  float* fsrc = (float*)alloc((size_t)N_NODES * HD * 4);
  ushort* fsrc16 = (ushort*)alloc((size_t)N_NODES * HD * 2);
  float* escore = (float*)alloc((size_t)N_EDGES * 8 * 4);
  float* val = (float*)alloc((size_t)N_EDGES * 4);
  int* cnt = (int*)alloc((size_t)4 * N_NODES * 4);
  int* rp_s = (int*)alloc((size_t)(N_NODES + 1) * 4);
  int* rp_d = (int*)alloc((size_t)(N_NODES + 1) * 4);
  int* cs = (int*)alloc((size_t)N_EDGES * 4);
  int* cd = (int*)alloc((size_t)N_EDGES * 4);
  int* keys_s = (int*)alloc((size_t)N_EDGES * 4);
  float* aval = (float*)alloc((size_t)N_EDGES * 4);
  float* thresh = (float*)alloc((size_t)N_NODES * 4);
  int* grp_off = (int*)alloc((size_t)N_NODES * NGRP * 4);
  unsigned char* cond = (unsigned char*)alloc((size_t)N_EDGES);
  if (off > ws_size) return;

  int* cnt_s = cnt;
  int* cnt_d = cnt + N_NODES;
  int* fill_s = cnt + 2 * N_NODES;
  int* fill_d = cnt + 3 * N_NODES;

  hipMemsetAsync(cnt, 0, (size_t)4 * N_NODES * 4, stream);
  histo<<<N_EDGES / 256, 256, 0, stream>>>(src, dst, cnt_s, cnt_d);
  scan2<<<2, 1024, 0, stream>>>(cnt_s, cnt_d, rp_s, rp_d);
  scatter_csr<<<N_EDGES / 256, 256, 0, stream>>>(src, dst, rp_s, rp_d, fill_s, fill_d, cs, cd);
  sort_rows_bitonic<<<(2 * N_NODES * 64) / 256, 256, 0, stream>>>(rp_s, rp_d, dst, cs, cd, keys_s, grp_off);
  gemm_nt<<<dim3(N_NODES / 128, HD / 128), 512, 0, stream>>>(feat, fcw, fsrc, fsrc16);
  edge_scores_grp<<<NGRP * (N_NODES / 4), 256, 0, stream>>>(fsrc, dst, trans, rp_s, cs, grp_off, escore, val);
  topk_wave<<<(N_NODES * 64) / 256, 256, 0, stream>>>(rp_s, keys_s, val, aval, thresh);
  cond_edges<<<N_EDGES / 256, 256, 0, stream>>>(src, dst, rp_s, keys_s, aval, thresh, cond);
  dst_softmax_agg<<<N_NODES / 4, 256, 0, stream>>>(rp_d, cd, src, cond, escore, fsrc16, out);
}